// Round 1
// baseline (570.317 us; speedup 1.0000x reference)
//
#include <hip/hip_runtime.h>
#include <hip/hip_bf16.h>

using f32x4 = __attribute__((ext_vector_type(4))) float;
using s16x8 = __attribute__((ext_vector_type(8))) short;
using s16x4 = __attribute__((ext_vector_type(4))) short;

#define B_ 2
#define C_ 256
#define N_ 4096

__device__ inline unsigned short f2bf(float f) {
    union { float f; unsigned u; } x{f};
    unsigned r = x.u + 0x7fffu + ((x.u >> 16) & 1u);
    return (unsigned short)(r >> 16);
}

// ---------------- GroupNorm: x (b,c,h,w,d) -> hn_t[b][n][c] bf16 ----------------
__global__ __launch_bounds__(256) void gn_kernel(const float* __restrict__ x,
                                                 const float* __restrict__ gamma,
                                                 const float* __restrict__ beta,
                                                 unsigned short* __restrict__ hn_t) {
    int blk = blockIdx.x;            // b*32 + group
    int b = blk >> 5, grp = blk & 31;
    const float* xb = x + ((size_t)b * C_ + grp * 8) * N_;   // 8 channels x 4096
    int t = threadIdx.x;

    float s = 0.f, sq = 0.f;
    const float4* x4 = (const float4*)xb;
    for (int i = 0; i < 32; ++i) {
        float4 v = x4[t + i * 256];
        s += v.x + v.y + v.z + v.w;
        sq += v.x * v.x + v.y * v.y + v.z * v.z + v.w * v.w;
    }
    for (int off = 32; off; off >>= 1) {
        s += __shfl_down(s, off);
        sq += __shfl_down(sq, off);
    }
    __shared__ float red[2][4];
    int wid = t >> 6;
    if ((t & 63) == 0) { red[0][wid] = s; red[1][wid] = sq; }
    __syncthreads();
    __shared__ float stats[2];
    if (t == 0) {
        float S = red[0][0] + red[0][1] + red[0][2] + red[0][3];
        float Q = red[1][0] + red[1][1] + red[1][2] + red[1][3];
        float mean = S / 32768.f;
        float var = Q / 32768.f - mean * mean;
        stats[0] = mean;
        stats[1] = rsqrtf(var + 1e-6f);
    }
    __syncthreads();
    float mean = stats[0], rstd = stats[1];

    float gm[8], bt[8];
    for (int j = 0; j < 8; ++j) {
        gm[j] = gamma[grp * 8 + j] * rstd;
        bt[j] = beta[grp * 8 + j] - mean * gm[j];
    }
    unsigned short* outp = hn_t + (size_t)b * N_ * C_ + grp * 8;
    for (int i = 0; i < 16; ++i) {
        int n = t + i * 256;
        s16x8 pk;
        for (int j = 0; j < 8; ++j) {
            float v = xb[(size_t)j * N_ + n];
            pk[j] = (short)f2bf(v * gm[j] + bt[j]);
        }
        *(s16x8*)(outp + (size_t)n * C_) = pk;
    }
}

// ---------------- GEMM: out = W(256x256) * B^T + bias ----------------
// Bsrc layout: [col(n)][k(c)] bf16, per batch N_*C_.
// MODE 0: bf16 out, transposed [n][o], scaled     (Q: scale=1/16, K: scale=1)
// MODE 1: bf16 out, natural   [o][n]              (V)
// MODE 2: f32  out, natural   [o][n], + resid     (final proj)
template <int MODE>
__global__ __launch_bounds__(256) void gemm_kernel(const float* __restrict__ W,
                                                   const float* __restrict__ bias,
                                                   const unsigned short* __restrict__ Bsrc,
                                                   unsigned short* __restrict__ outb,
                                                   float* __restrict__ outf,
                                                   const float* __restrict__ resid,
                                                   float scale) {
    int nblk = blockIdx.x;   // 0..31
    int oblk = blockIdx.y;   // 0..1
    int b = blockIdx.z;
    const unsigned short* Bb = Bsrc + (size_t)b * N_ * C_;

    __shared__ unsigned short As[128][72];   // padded stride
    int t = threadIdx.x;
    int lane = t & 63, w = t >> 6;
    int wr = w >> 1, wc = w & 1;
    int l15 = lane & 15, lg = lane >> 4;
    int o0 = oblk * 128, n0 = nblk * 128;

    f32x4 acc[4][4];
    for (int mi = 0; mi < 4; ++mi)
        for (int ni = 0; ni < 4; ++ni)
            acc[mi][ni] = (f32x4){0.f, 0.f, 0.f, 0.f};

    for (int k0 = 0; k0 < 256; k0 += 64) {
        __syncthreads();
        for (int i = 0; i < 8; ++i) {
            int idx = t + i * 256;            // 0..2047
            int r = idx >> 4;                 // row 0..127
            int c4 = (idx & 15) << 2;         // col 0..60 step 4
            float4 wv = *(const float4*)(W + (size_t)(o0 + r) * 256 + k0 + c4);
            s16x4 pk;
            pk[0] = (short)f2bf(wv.x); pk[1] = (short)f2bf(wv.y);
            pk[2] = (short)f2bf(wv.z); pk[3] = (short)f2bf(wv.w);
            *(s16x4*)(&As[r][c4]) = pk;
        }
        __syncthreads();
        for (int kk = 0; kk < 2; ++kk) {
            s16x8 af[4], bfr[4];
            for (int mi = 0; mi < 4; ++mi)
                af[mi] = *(const s16x8*)(&As[wr * 64 + mi * 16 + l15][kk * 32 + lg * 8]);
            for (int ni = 0; ni < 4; ++ni)
                bfr[ni] = *(const s16x8*)(Bb + (size_t)(n0 + wc * 64 + ni * 16 + l15) * C_ + k0 + kk * 32 + lg * 8);
            for (int mi = 0; mi < 4; ++mi)
                for (int ni = 0; ni < 4; ++ni)
                    acc[mi][ni] = __builtin_amdgcn_mfma_f32_16x16x32_bf16(af[mi], bfr[ni], acc[mi][ni], 0, 0, 0);
        }
    }

    for (int mi = 0; mi < 4; ++mi) {
        int obase = o0 + wr * 64 + mi * 16 + lg * 4;
        for (int ni = 0; ni < 4; ++ni) {
            int n = n0 + wc * 64 + ni * 16 + l15;
            for (int r = 0; r < 4; ++r) {
                int o = obase + r;
                float val = (acc[mi][ni][r] + bias[o]) * scale;
                if (MODE == 0) {
                    outb[(size_t)b * N_ * C_ + (size_t)n * C_ + o] = f2bf(val);
                } else if (MODE == 1) {
                    outb[(size_t)b * N_ * C_ + (size_t)o * N_ + n] = f2bf(val);
                } else {
                    size_t idx = (size_t)b * N_ * C_ + (size_t)o * N_ + n;
                    outf[idx] = resid[idx] + val;
                }
            }
        }
    }
}

// ---------------- Flash attention ----------------
// Qt,Kt: [b][n][c] bf16 (Q pre-scaled by 1/16), V: [b][c][m] bf16.
// Out: ao[b][n][c] bf16.
__global__ __launch_bounds__(256) void attn_kernel(const unsigned short* __restrict__ qt,
                                                   const unsigned short* __restrict__ kt,
                                                   const unsigned short* __restrict__ vv,
                                                   unsigned short* __restrict__ ao) {
    int b = blockIdx.y;
    int t = threadIdx.x;
    int lane = t & 63, w = t >> 6;
    int l15 = lane & 15, lg = lane >> 4;
    int n0 = blockIdx.x * 64 + w * 16;      // this wave's 16 query rows
    const size_t off = (size_t)b * N_ * C_;
    const unsigned short* Q = qt + off;
    const unsigned short* K = kt + off;
    const unsigned short* V = vv + off;

    __shared__ unsigned short P_all[4][16][72];
    unsigned short(*P_lds)[72] = P_all[w];

    s16x8 q[8];
    for (int f = 0; f < 8; ++f)
        q[f] = *(const s16x8*)(Q + (size_t)(n0 + l15) * C_ + f * 32 + lg * 8);

    f32x4 O[16];
    for (int i = 0; i < 16; ++i) O[i] = (f32x4){0.f, 0.f, 0.f, 0.f};
    float mrun[4], lrun[4];
    for (int r = 0; r < 4; ++r) { mrun[r] = -1e30f; lrun[r] = 0.f; }

    for (int m0 = 0; m0 < N_; m0 += 64) {
        // S = Q K^T for 16 rows x 64 keys
        f32x4 S[4];
        for (int f = 0; f < 4; ++f) {
            f32x4 s = (f32x4){0.f, 0.f, 0.f, 0.f};
            const unsigned short* Krow = K + (size_t)(m0 + f * 16 + l15) * C_ + lg * 8;
            for (int kc = 0; kc < 8; ++kc) {
                s16x8 kb = *(const s16x8*)(Krow + kc * 32);
                s = __builtin_amdgcn_mfma_f32_16x16x32_bf16(q[kc], kb, s, 0, 0, 0);
            }
            S[f] = s;
        }
        // online softmax (rows live in regs r, cols across lane&15 and frag f)
        float alpha[4];
        for (int r = 0; r < 4; ++r) {
            float mx = fmaxf(fmaxf(S[0][r], S[1][r]), fmaxf(S[2][r], S[3][r]));
            mx = fmaxf(mx, __shfl_xor(mx, 1));
            mx = fmaxf(mx, __shfl_xor(mx, 2));
            mx = fmaxf(mx, __shfl_xor(mx, 4));
            mx = fmaxf(mx, __shfl_xor(mx, 8));
            float newm = fmaxf(mrun[r], mx);
            alpha[r] = __expf(mrun[r] - newm);
            mrun[r] = newm;
            float rs = 0.f;
            for (int f = 0; f < 4; ++f) {
                float p = __expf(S[f][r] - newm);
                S[f][r] = p;
                rs += p;
            }
            rs += __shfl_xor(rs, 1);
            rs += __shfl_xor(rs, 2);
            rs += __shfl_xor(rs, 4);
            rs += __shfl_xor(rs, 8);
            lrun[r] = lrun[r] * alpha[r] + rs;
        }
        for (int i = 0; i < 16; ++i)
            for (int r = 0; r < 4; ++r) O[i][r] *= alpha[r];

        // P (C-layout) -> LDS -> A-layout bf16
        for (int f = 0; f < 4; ++f)
            for (int r = 0; r < 4; ++r)
                P_lds[lg * 4 + r][f * 16 + l15] = f2bf(S[f][r]);
        asm volatile("s_waitcnt lgkmcnt(0)" ::: "memory");
        s16x8 pa[2];
        for (int ks = 0; ks < 2; ++ks)
            pa[ks] = *(const s16x8*)(&P_lds[l15][ks * 32 + lg * 8]);
        asm volatile("" ::: "memory");

        // O += P * V^T   (B[k=m][col=c] = V[c][m])
        for (int cb = 0; cb < 16; ++cb) {
            const unsigned short* Vrow = V + (size_t)(cb * 16 + l15) * N_ + m0 + lg * 8;
            for (int ks = 0; ks < 2; ++ks) {
                s16x8 vb = *(const s16x8*)(Vrow + ks * 32);
                O[cb] = __builtin_amdgcn_mfma_f32_16x16x32_bf16(pa[ks], vb, O[cb], 0, 0, 0);
            }
        }
    }

    unsigned short* AO = ao + off;
    for (int cb = 0; cb < 16; ++cb) {
        for (int r = 0; r < 4; ++r) {
            float val = O[cb][r] / lrun[r];
            int n = n0 + lg * 4 + r;
            AO[(size_t)n * C_ + cb * 16 + l15] = f2bf(val);
        }
    }
}

extern "C" void kernel_launch(void* const* d_in, const int* in_sizes, int n_in,
                              void* d_out, int out_size, void* d_ws, size_t ws_size,
                              hipStream_t stream) {
    const float* x = (const float*)d_in[0];
    const float* gamma = (const float*)d_in[1];
    const float* beta = (const float*)d_in[2];
    const float* wq = (const float*)d_in[3];
    const float* bq = (const float*)d_in[4];
    const float* wk = (const float*)d_in[5];
    const float* bk = (const float*)d_in[6];
    const float* wv = (const float*)d_in[7];
    const float* bv = (const float*)d_in[8];
    const float* wp = (const float*)d_in[9];
    const float* bp = (const float*)d_in[10];
    float* out = (float*)d_out;

    const size_t sz = (size_t)B_ * N_ * C_;
    unsigned short* hn = (unsigned short*)d_ws;  // [b][n][c]
    unsigned short* qt = hn + sz;                // [b][n][c], scaled
    unsigned short* kt = qt + sz;                // [b][n][c]
    unsigned short* vmat = kt + sz;              // [b][c][m]
    unsigned short* ao = vmat + sz;              // [b][n][c]

    hipLaunchKernelGGL(gn_kernel, dim3(64), dim3(256), 0, stream, x, gamma, beta, hn);
    dim3 gg(32, 2, 2);
    hipLaunchKernelGGL((gemm_kernel<0>), gg, dim3(256), 0, stream, wq, bq, hn, qt, (float*)nullptr, (const float*)nullptr, 0.0625f);
    hipLaunchKernelGGL((gemm_kernel<0>), gg, dim3(256), 0, stream, wk, bk, hn, kt, (float*)nullptr, (const float*)nullptr, 1.0f);
    hipLaunchKernelGGL((gemm_kernel<1>), gg, dim3(256), 0, stream, wv, bv, hn, vmat, (float*)nullptr, (const float*)nullptr, 1.0f);
    hipLaunchKernelGGL(attn_kernel, dim3(64, 2), dim3(256), 0, stream, qt, kt, vmat, ao);
    hipLaunchKernelGGL((gemm_kernel<2>), gg, dim3(256), 0, stream, wp, bp, ao, (unsigned short*)nullptr, out, x, 1.0f);
}

// Round 2
// 354.845 us; speedup vs baseline: 1.6072x; 1.6072x over previous
//
#include <hip/hip_runtime.h>
#include <hip/hip_bf16.h>

using f32x4 = __attribute__((ext_vector_type(4))) float;
using s16x8 = __attribute__((ext_vector_type(8))) short;
using s16x4 = __attribute__((ext_vector_type(4))) short;

#define B_ 2
#define C_ 256
#define N_ 4096

__device__ inline unsigned short f2bf(float f) {
    union { float f; unsigned u; } x{f};
    unsigned r = x.u + 0x7fffu + ((x.u >> 16) & 1u);
    return (unsigned short)(r >> 16);
}

// ---------------- GroupNorm: x (b,c,h,w,d) -> hn_t[b][n][c] bf16 ----------------
__global__ __launch_bounds__(256) void gn_kernel(const float* __restrict__ x,
                                                 const float* __restrict__ gamma,
                                                 const float* __restrict__ beta,
                                                 unsigned short* __restrict__ hn_t) {
    int blk = blockIdx.x;            // b*32 + group
    int b = blk >> 5, grp = blk & 31;
    const float* xb = x + ((size_t)b * C_ + grp * 8) * N_;   // 8 channels x 4096
    int t = threadIdx.x;

    float s = 0.f, sq = 0.f;
    const float4* x4 = (const float4*)xb;
    for (int i = 0; i < 32; ++i) {
        float4 v = x4[t + i * 256];
        s += v.x + v.y + v.z + v.w;
        sq += v.x * v.x + v.y * v.y + v.z * v.z + v.w * v.w;
    }
    for (int off = 32; off; off >>= 1) {
        s += __shfl_down(s, off);
        sq += __shfl_down(sq, off);
    }
    __shared__ float red[2][4];
    int wid = t >> 6;
    if ((t & 63) == 0) { red[0][wid] = s; red[1][wid] = sq; }
    __syncthreads();
    __shared__ float stats[2];
    if (t == 0) {
        float S = red[0][0] + red[0][1] + red[0][2] + red[0][3];
        float Q = red[1][0] + red[1][1] + red[1][2] + red[1][3];
        float mean = S / 32768.f;
        float var = Q / 32768.f - mean * mean;
        stats[0] = mean;
        stats[1] = rsqrtf(var + 1e-6f);
    }
    __syncthreads();
    float mean = stats[0], rstd = stats[1];

    float gm[8], bt[8];
    for (int j = 0; j < 8; ++j) {
        gm[j] = gamma[grp * 8 + j] * rstd;
        bt[j] = beta[grp * 8 + j] - mean * gm[j];
    }
    unsigned short* outp = hn_t + (size_t)b * N_ * C_ + grp * 8;
    for (int i = 0; i < 16; ++i) {
        int n = t + i * 256;
        s16x8 pk;
        for (int j = 0; j < 8; ++j) {
            float v = xb[(size_t)j * N_ + n];
            pk[j] = (short)f2bf(v * gm[j] + bt[j]);
        }
        *(s16x8*)(outp + (size_t)n * C_) = pk;
    }
}

// ---------------- GEMM: out = W(256x256) * B^T + bias ----------------
// Bsrc layout: [col(n)][k(c)] bf16, per batch N_*C_.
// MODE 0: bf16 out, transposed [n][o], scaled     (Q: scale=1/16, K: scale=1)
// MODE 1: bf16 out, natural   [o][n]              (V)
// MODE 2: f32  out, natural   [o][n], + resid     (final proj)
template <int MODE>
__global__ __launch_bounds__(256) void gemm_kernel(const float* __restrict__ W,
                                                   const float* __restrict__ bias,
                                                   const unsigned short* __restrict__ Bsrc,
                                                   unsigned short* __restrict__ outb,
                                                   float* __restrict__ outf,
                                                   const float* __restrict__ resid,
                                                   float scale) {
    int nblk = blockIdx.x;   // 0..63  (n-tile 64)
    int oblk = blockIdx.y;   // 0..1
    int b = blockIdx.z;
    const unsigned short* Bb = Bsrc + (size_t)b * N_ * C_;

    __shared__ unsigned short As[128][72];   // padded stride
    int t = threadIdx.x;
    int lane = t & 63, w = t >> 6;
    int wr = w >> 1, wc = w & 1;
    int l15 = lane & 15, lg = lane >> 4;
    int o0 = oblk * 128, n0 = nblk * 64;

    f32x4 acc[4][2];
    for (int mi = 0; mi < 4; ++mi)
        for (int ni = 0; ni < 2; ++ni)
            acc[mi][ni] = (f32x4){0.f, 0.f, 0.f, 0.f};

    for (int k0 = 0; k0 < 256; k0 += 64) {
        __syncthreads();
        for (int i = 0; i < 8; ++i) {
            int idx = t + i * 256;            // 0..2047
            int r = idx >> 4;                 // row 0..127
            int c4 = (idx & 15) << 2;         // col 0..60 step 4
            float4 wv = *(const float4*)(W + (size_t)(o0 + r) * 256 + k0 + c4);
            s16x4 pk;
            pk[0] = (short)f2bf(wv.x); pk[1] = (short)f2bf(wv.y);
            pk[2] = (short)f2bf(wv.z); pk[3] = (short)f2bf(wv.w);
            *(s16x4*)(&As[r][c4]) = pk;
        }
        __syncthreads();
        for (int kk = 0; kk < 2; ++kk) {
            s16x8 af[4], bfr[2];
            for (int mi = 0; mi < 4; ++mi)
                af[mi] = *(const s16x8*)(&As[wr * 64 + mi * 16 + l15][kk * 32 + lg * 8]);
            for (int ni = 0; ni < 2; ++ni)
                bfr[ni] = *(const s16x8*)(Bb + (size_t)(n0 + wc * 32 + ni * 16 + l15) * C_ + k0 + kk * 32 + lg * 8);
            for (int mi = 0; mi < 4; ++mi)
                for (int ni = 0; ni < 2; ++ni)
                    acc[mi][ni] = __builtin_amdgcn_mfma_f32_16x16x32_bf16(af[mi], bfr[ni], acc[mi][ni], 0, 0, 0);
        }
    }

    for (int mi = 0; mi < 4; ++mi) {
        int obase = o0 + wr * 64 + mi * 16 + lg * 4;
        for (int ni = 0; ni < 2; ++ni) {
            int n = n0 + wc * 32 + ni * 16 + l15;
            for (int r = 0; r < 4; ++r) {
                int o = obase + r;
                float val = (acc[mi][ni][r] + bias[o]) * scale;
                if (MODE == 0) {
                    outb[(size_t)b * N_ * C_ + (size_t)n * C_ + o] = f2bf(val);
                } else if (MODE == 1) {
                    outb[(size_t)b * N_ * C_ + (size_t)o * N_ + n] = f2bf(val);
                } else {
                    size_t idx = (size_t)b * N_ * C_ + (size_t)o * N_ + n;
                    outf[idx] = resid[idx] + val;
                }
            }
        }
    }
}

// ---------------- Flash attention, KV-split partial ----------------
// Qt,Kt: [b][n][c] bf16 (Q pre-scaled by 1/16), V: [b][c][m] bf16.
// Writes unnormalized O (f32) + per-row (m,l).
__global__ __launch_bounds__(256) void attn_partial_kernel(const unsigned short* __restrict__ qt,
                                                           const unsigned short* __restrict__ kt,
                                                           const unsigned short* __restrict__ vv,
                                                           float* __restrict__ Opart,
                                                           float* __restrict__ ml,
                                                           int kvlen) {
    int b = blockIdx.z;
    int split = blockIdx.y;
    int nsplit = gridDim.y;
    int t = threadIdx.x;
    int lane = t & 63, w = t >> 6;
    int l15 = lane & 15, lg = lane >> 4;
    int n0 = blockIdx.x * 64 + w * 16;      // this wave's 16 query rows
    const size_t off = (size_t)b * N_ * C_;
    const unsigned short* Q = qt + off;
    const unsigned short* K = kt + off;
    const unsigned short* V = vv + off;

    __shared__ unsigned short P_all[4][16][72];
    unsigned short(*P_lds)[72] = P_all[w];

    s16x8 q[8];
    for (int f = 0; f < 8; ++f)
        q[f] = *(const s16x8*)(Q + (size_t)(n0 + l15) * C_ + f * 32 + lg * 8);

    f32x4 O[16];
    for (int i = 0; i < 16; ++i) O[i] = (f32x4){0.f, 0.f, 0.f, 0.f};
    float mrun[4], lrun[4];
    for (int r = 0; r < 4; ++r) { mrun[r] = -1e30f; lrun[r] = 0.f; }

    int m0start = split * kvlen;
    for (int m0 = m0start; m0 < m0start + kvlen; m0 += 64) {
        // S = Q K^T for 16 rows x 64 keys
        f32x4 S[4];
        for (int f = 0; f < 4; ++f) {
            f32x4 s = (f32x4){0.f, 0.f, 0.f, 0.f};
            const unsigned short* Krow = K + (size_t)(m0 + f * 16 + l15) * C_ + lg * 8;
            for (int kc = 0; kc < 8; ++kc) {
                s16x8 kb = *(const s16x8*)(Krow + kc * 32);
                s = __builtin_amdgcn_mfma_f32_16x16x32_bf16(q[kc], kb, s, 0, 0, 0);
            }
            S[f] = s;
        }
        // online softmax (rows live in regs r, cols across lane&15 and frag f)
        float alpha[4];
        for (int r = 0; r < 4; ++r) {
            float mx = fmaxf(fmaxf(S[0][r], S[1][r]), fmaxf(S[2][r], S[3][r]));
            mx = fmaxf(mx, __shfl_xor(mx, 1));
            mx = fmaxf(mx, __shfl_xor(mx, 2));
            mx = fmaxf(mx, __shfl_xor(mx, 4));
            mx = fmaxf(mx, __shfl_xor(mx, 8));
            float newm = fmaxf(mrun[r], mx);
            alpha[r] = __expf(mrun[r] - newm);
            mrun[r] = newm;
            float rs = 0.f;
            for (int f = 0; f < 4; ++f) {
                float p = __expf(S[f][r] - newm);
                S[f][r] = p;
                rs += p;
            }
            rs += __shfl_xor(rs, 1);
            rs += __shfl_xor(rs, 2);
            rs += __shfl_xor(rs, 4);
            rs += __shfl_xor(rs, 8);
            lrun[r] = lrun[r] * alpha[r] + rs;
        }
        for (int i = 0; i < 16; ++i)
            for (int r = 0; r < 4; ++r) O[i][r] *= alpha[r];

        // P (C-layout) -> LDS -> A-layout bf16
        for (int f = 0; f < 4; ++f)
            for (int r = 0; r < 4; ++r)
                P_lds[lg * 4 + r][f * 16 + l15] = f2bf(S[f][r]);
        asm volatile("s_waitcnt lgkmcnt(0)" ::: "memory");
        s16x8 pa[2];
        for (int ks = 0; ks < 2; ++ks)
            pa[ks] = *(const s16x8*)(&P_lds[l15][ks * 32 + lg * 8]);
        asm volatile("" ::: "memory");

        // O += P * V^T   (B[k=m][col=c] = V[c][m])
        for (int cb = 0; cb < 16; ++cb) {
            const unsigned short* Vrow = V + (size_t)(cb * 16 + l15) * N_ + m0 + lg * 8;
            for (int ks = 0; ks < 2; ++ks) {
                s16x8 vb = *(const s16x8*)(Vrow + ks * 32);
                O[cb] = __builtin_amdgcn_mfma_f32_16x16x32_bf16(pa[ks], vb, O[cb], 0, 0, 0);
            }
        }
    }

    float* Ob = Opart + (size_t)(b * nsplit + split) * N_ * C_;
    float* mlb = ml + (size_t)(b * nsplit + split) * N_ * 2;
    for (int cb = 0; cb < 16; ++cb)
        for (int r = 0; r < 4; ++r)
            Ob[(size_t)(n0 + lg * 4 + r) * C_ + cb * 16 + l15] = O[cb][r];
    if (l15 == 0)
        for (int r = 0; r < 4; ++r) {
            int n = n0 + lg * 4 + r;
            mlb[(size_t)n * 2] = mrun[r];
            mlb[(size_t)n * 2 + 1] = lrun[r];
        }
}

// ---------------- merge partials -> ao bf16 [b][n][c] ----------------
__global__ __launch_bounds__(256) void attn_merge_kernel(const float* __restrict__ Opart,
                                                         const float* __restrict__ ml,
                                                         unsigned short* __restrict__ ao,
                                                         int nsplit) {
    int b = blockIdx.y;
    int n = blockIdx.x;
    int c = threadIdx.x;
    float M = -1e30f;
    for (int s = 0; s < nsplit; ++s)
        M = fmaxf(M, ml[((size_t)(b * nsplit + s) * N_ + n) * 2]);
    float L = 0.f, o = 0.f;
    for (int s = 0; s < nsplit; ++s) {
        const float* mlp = ml + ((size_t)(b * nsplit + s) * N_ + n) * 2;
        float wgt = __expf(mlp[0] - M);
        L += mlp[1] * wgt;
        o += Opart[((size_t)(b * nsplit + s) * N_ + n) * C_ + c] * wgt;
    }
    ao[((size_t)b * N_ + n) * C_ + c] = f2bf(o / L);
}

extern "C" void kernel_launch(void* const* d_in, const int* in_sizes, int n_in,
                              void* d_out, int out_size, void* d_ws, size_t ws_size,
                              hipStream_t stream) {
    const float* x = (const float*)d_in[0];
    const float* gamma = (const float*)d_in[1];
    const float* beta = (const float*)d_in[2];
    const float* wq = (const float*)d_in[3];
    const float* bq = (const float*)d_in[4];
    const float* wk = (const float*)d_in[5];
    const float* bk = (const float*)d_in[6];
    const float* wv = (const float*)d_in[7];
    const float* bv = (const float*)d_in[8];
    const float* wp = (const float*)d_in[9];
    const float* bp = (const float*)d_in[10];
    float* out = (float*)d_out;

    const size_t sz = (size_t)B_ * N_ * C_;
    unsigned short* hn = (unsigned short*)d_ws;  // [b][n][c]
    unsigned short* qt = hn + sz;                // [b][n][c], scaled
    unsigned short* kt = qt + sz;                // [b][n][c]
    unsigned short* vmat = kt + sz;              // [b][c][m]
    unsigned short* ao = vmat + sz;              // [b][n][c]
    float* Opart = (float*)(ao + sz);            // [b][s][n][c] f32, unnormalized
    // pick the largest KV-split count whose partial buffers fit in ws
    int nsplit = 8;
    while (nsplit > 1 &&
           (size_t)5 * sz * 2 + (size_t)nsplit * sz * 4 + (size_t)nsplit * B_ * N_ * 2 * 4 > ws_size)
        nsplit >>= 1;
    float* ml = Opart + (size_t)nsplit * sz;     // [b][s][n][2]

    hipLaunchKernelGGL(gn_kernel, dim3(64), dim3(256), 0, stream, x, gamma, beta, hn);
    dim3 gg(64, 2, 2);
    hipLaunchKernelGGL((gemm_kernel<0>), gg, dim3(256), 0, stream, wq, bq, hn, qt, (float*)nullptr, (const float*)nullptr, 0.0625f);
    hipLaunchKernelGGL((gemm_kernel<0>), gg, dim3(256), 0, stream, wk, bk, hn, kt, (float*)nullptr, (const float*)nullptr, 1.0f);
    hipLaunchKernelGGL((gemm_kernel<1>), gg, dim3(256), 0, stream, wv, bv, hn, vmat, (float*)nullptr, (const float*)nullptr, 1.0f);
    hipLaunchKernelGGL(attn_partial_kernel, dim3(64, nsplit, 2), dim3(256), 0, stream,
                       qt, kt, vmat, Opart, ml, N_ / nsplit);
    hipLaunchKernelGGL(attn_merge_kernel, dim3(N_, 2), dim3(256), 0, stream, Opart, ml, ao, nsplit);
    hipLaunchKernelGGL((gemm_kernel<2>), gg, dim3(256), 0, stream, wp, bp, ao, (unsigned short*)nullptr, out, x, 1.0f);
}

// Round 3
// 185.425 us; speedup vs baseline: 3.0757x; 1.9137x over previous
//
#include <hip/hip_runtime.h>
#include <hip/hip_bf16.h>

using f32x4 = __attribute__((ext_vector_type(4))) float;
using s16x8 = __attribute__((ext_vector_type(8))) short;
using s16x4 = __attribute__((ext_vector_type(4))) short;

#define B_ 2
#define C_ 256
#define N_ 4096
#define KVB 32

__device__ inline unsigned short f2bf(float f) {
    union { float f; unsigned u; } x{f};
    unsigned r = x.u + 0x7fffu + ((x.u >> 16) & 1u);
    return (unsigned short)(r >> 16);
}

__device__ inline void load_lds16(const void* g, void* l) {
    __builtin_amdgcn_global_load_lds((const __attribute__((address_space(1))) void*)g,
                                     (__attribute__((address_space(3))) void*)l, 16, 0, 0);
}

// ---------------- GroupNorm: x (b,c,h,w,d) -> hn_t[b][n][c] bf16 ----------------
__global__ __launch_bounds__(256) void gn_kernel(const float* __restrict__ x,
                                                 const float* __restrict__ gamma,
                                                 const float* __restrict__ beta,
                                                 unsigned short* __restrict__ hn_t) {
    int blk = blockIdx.x;            // b*32 + group
    int b = blk >> 5, grp = blk & 31;
    const float* xb = x + ((size_t)b * C_ + grp * 8) * N_;   // 8 channels x 4096
    int t = threadIdx.x;

    float s = 0.f, sq = 0.f;
    const float4* x4 = (const float4*)xb;
    for (int i = 0; i < 32; ++i) {
        float4 v = x4[t + i * 256];
        s += v.x + v.y + v.z + v.w;
        sq += v.x * v.x + v.y * v.y + v.z * v.z + v.w * v.w;
    }
    for (int off = 32; off; off >>= 1) {
        s += __shfl_down(s, off);
        sq += __shfl_down(sq, off);
    }
    __shared__ float red[2][4];
    int wid = t >> 6;
    if ((t & 63) == 0) { red[0][wid] = s; red[1][wid] = sq; }
    __syncthreads();
    __shared__ float stats[2];
    if (t == 0) {
        float S = red[0][0] + red[0][1] + red[0][2] + red[0][3];
        float Q = red[1][0] + red[1][1] + red[1][2] + red[1][3];
        float mean = S / 32768.f;
        float var = Q / 32768.f - mean * mean;
        stats[0] = mean;
        stats[1] = rsqrtf(var + 1e-6f);
    }
    __syncthreads();
    float mean = stats[0], rstd = stats[1];

    float gm[8], bt[8];
    for (int j = 0; j < 8; ++j) {
        gm[j] = gamma[grp * 8 + j] * rstd;
        bt[j] = beta[grp * 8 + j] - mean * gm[j];
    }
    unsigned short* outp = hn_t + (size_t)b * N_ * C_ + grp * 8;
    for (int i = 0; i < 16; ++i) {
        int n = t + i * 256;
        s16x8 pk;
        for (int j = 0; j < 8; ++j) {
            float v = xb[(size_t)j * N_ + n];
            pk[j] = (short)f2bf(v * gm[j] + bt[j]);
        }
        *(s16x8*)(outp + (size_t)n * C_) = pk;
    }
}

// ---------------- GEMM: out = W(256x256) * B^T + bias ----------------
template <int MODE>
__global__ __launch_bounds__(256) void gemm_kernel(const float* __restrict__ W,
                                                   const float* __restrict__ bias,
                                                   const unsigned short* __restrict__ Bsrc,
                                                   unsigned short* __restrict__ outb,
                                                   float* __restrict__ outf,
                                                   const float* __restrict__ resid,
                                                   float scale) {
    int nblk = blockIdx.x;   // 0..63  (n-tile 64)
    int oblk = blockIdx.y;   // 0..1
    int b = blockIdx.z;
    const unsigned short* Bb = Bsrc + (size_t)b * N_ * C_;

    __shared__ unsigned short As[128][72];   // padded stride
    int t = threadIdx.x;
    int lane = t & 63, w = t >> 6;
    int wr = w >> 1, wc = w & 1;
    int l15 = lane & 15, lg = lane >> 4;
    int o0 = oblk * 128, n0 = nblk * 64;

    f32x4 acc[4][2];
    for (int mi = 0; mi < 4; ++mi)
        for (int ni = 0; ni < 2; ++ni)
            acc[mi][ni] = (f32x4){0.f, 0.f, 0.f, 0.f};

    for (int k0 = 0; k0 < 256; k0 += 64) {
        __syncthreads();
        for (int i = 0; i < 8; ++i) {
            int idx = t + i * 256;            // 0..2047
            int r = idx >> 4;                 // row 0..127
            int c4 = (idx & 15) << 2;         // col 0..60 step 4
            float4 wv = *(const float4*)(W + (size_t)(o0 + r) * 256 + k0 + c4);
            s16x4 pk;
            pk[0] = (short)f2bf(wv.x); pk[1] = (short)f2bf(wv.y);
            pk[2] = (short)f2bf(wv.z); pk[3] = (short)f2bf(wv.w);
            *(s16x4*)(&As[r][c4]) = pk;
        }
        __syncthreads();
        for (int kk = 0; kk < 2; ++kk) {
            s16x8 af[4], bfr[2];
            for (int mi = 0; mi < 4; ++mi)
                af[mi] = *(const s16x8*)(&As[wr * 64 + mi * 16 + l15][kk * 32 + lg * 8]);
            for (int ni = 0; ni < 2; ++ni)
                bfr[ni] = *(const s16x8*)(Bb + (size_t)(n0 + wc * 32 + ni * 16 + l15) * C_ + k0 + kk * 32 + lg * 8);
            for (int mi = 0; mi < 4; ++mi)
                for (int ni = 0; ni < 2; ++ni)
                    acc[mi][ni] = __builtin_amdgcn_mfma_f32_16x16x32_bf16(af[mi], bfr[ni], acc[mi][ni], 0, 0, 0);
        }
    }

    for (int mi = 0; mi < 4; ++mi) {
        int obase = o0 + wr * 64 + mi * 16 + lg * 4;
        for (int ni = 0; ni < 2; ++ni) {
            int n = n0 + wc * 32 + ni * 16 + l15;
            for (int r = 0; r < 4; ++r) {
                int o = obase + r;
                float val = (acc[mi][ni][r] + bias[o]) * scale;
                if (MODE == 0) {
                    outb[(size_t)b * N_ * C_ + (size_t)n * C_ + o] = f2bf(val);
                } else if (MODE == 1) {
                    outb[(size_t)b * N_ * C_ + (size_t)o * N_ + n] = f2bf(val);
                } else {
                    size_t idx = (size_t)b * N_ * C_ + (size_t)o * N_ + n;
                    outf[idx] = resid[idx] + val;
                }
            }
        }
    }
}

// ---------------- Flash attention, KV-split, LDS-staged K/V ----------------
// Qt,Kt: [b][n][c] bf16 (Q pre-scaled by 1/16), V: [b][c][m] bf16.
// K tile [KVB][256] in LDS, byte XOR swizzle ((row&7)<<4)   (row = byte>>9)
// V tile [256][KVB] in LDS, byte XOR swizzle (((row>>1)&3)<<4) (row = byte>>6, pair = byte>>7)
// Both staged linearly via global_load_lds with inverse-swizzled SOURCE addresses.
__global__ __launch_bounds__(256) void attn_partial_kernel(const unsigned short* __restrict__ qt,
                                                           const unsigned short* __restrict__ kt,
                                                           const unsigned short* __restrict__ vv,
                                                           float* __restrict__ Opart,
                                                           float* __restrict__ ml,
                                                           int kvlen) {
    int b = blockIdx.z;
    int split = blockIdx.y;
    int nsplit = gridDim.y;
    int t = threadIdx.x;
    int lane = t & 63, w = t >> 6;
    int l15 = lane & 15, lg = lane >> 4;
    int n0 = blockIdx.x * 64 + w * 16;      // this wave's 16 query rows
    const size_t off = (size_t)b * N_ * C_;
    const unsigned short* Q = qt + off;
    const unsigned short* K = kt + off;
    const unsigned short* V = vv + off;

    __shared__ unsigned short Ktile[2][KVB * 256];
    __shared__ unsigned short Vtile[2][256 * KVB];
    __shared__ unsigned short P_all[4][16][40];
    unsigned short(*P_lds)[40] = P_all[w];

    s16x8 q[8];
    for (int f = 0; f < 8; ++f)
        q[f] = *(const s16x8*)(Q + (size_t)(n0 + l15) * C_ + f * 32 + lg * 8);

    f32x4 O[16];
    for (int i = 0; i < 16; ++i) O[i] = (f32x4){0.f, 0.f, 0.f, 0.f};
    float mrun[4], lrun[4];
    for (int r = 0; r < 4; ++r) { mrun[r] = -1e30f; lrun[r] = 0.f; }

    const char* Kg0 = (const char*)K;
    const char* Vg0 = (const char*)V;

    // stage one KV tile (16KB K + 16KB V) into buffer `buf`
    auto stage = [&](int buf, int m0) {
        const char* Kg = Kg0 + (size_t)m0 * 512;       // rows contiguous
        char* Kl = (char*)&Ktile[buf][0];
        for (int i = 0; i < 4; ++i) {
            int base = i * 4096 + w * 1024;            // wave-uniform LDS base
            int o = base + lane * 16;
            int src = o ^ (((o >> 9) & 7) << 4);       // inverse swizzle on source
            load_lds16(Kg + src, Kl + base);
        }
        char* Vl = (char*)&Vtile[buf][0];
        for (int i = 0; i < 4; ++i) {
            int base = i * 4096 + w * 1024;
            int o = base + lane * 16;
            int y = o ^ (((o >> 7) & 3) << 4);         // inverse swizzle (logical offset)
            int row = y >> 6, within = y & 63;         // V tile row=c (64B per row)
            load_lds16(Vg0 + (size_t)row * (N_ * 2) + (size_t)m0 * 2 + within, Vl + base);
        }
    };

    int m0start = split * kvlen;
    int niter = kvlen / KVB;
    int cur = 0;
    stage(0, m0start);
    __syncthreads();   // drains vmcnt(0): tile 0 resident

    for (int it = 0; it < niter; ++it) {
        if (it + 1 < niter) stage(cur ^ 1, m0start + (it + 1) * KVB);  // async prefetch

        const char* Kl = (const char*)&Ktile[cur][0];
        const char* Vl = (const char*)&Vtile[cur][0];

        // S = Q K^T for 16 rows x KVB keys (2 col-fragments)
        f32x4 S[2];
        for (int f = 0; f < 2; ++f) {
            f32x4 s = (f32x4){0.f, 0.f, 0.f, 0.f};
            int row = f * 16 + l15;
            int swz = (row & 7) << 4;
            for (int kc = 0; kc < 8; ++kc) {
                int lo = row * 512 + kc * 64 + lg * 16;
                s16x8 kb = *(const s16x8*)(Kl + (lo ^ swz));
                s = __builtin_amdgcn_mfma_f32_16x16x32_bf16(q[kc], kb, s, 0, 0, 0);
            }
            S[f] = s;
        }

        // online softmax
        float alpha[4];
        for (int r = 0; r < 4; ++r) {
            float mx = fmaxf(S[0][r], S[1][r]);
            mx = fmaxf(mx, __shfl_xor(mx, 1));
            mx = fmaxf(mx, __shfl_xor(mx, 2));
            mx = fmaxf(mx, __shfl_xor(mx, 4));
            mx = fmaxf(mx, __shfl_xor(mx, 8));
            float newm = fmaxf(mrun[r], mx);
            alpha[r] = __expf(mrun[r] - newm);
            mrun[r] = newm;
            float rs = 0.f;
            for (int f = 0; f < 2; ++f) {
                float p = __expf(S[f][r] - newm);
                S[f][r] = p;
                rs += p;
            }
            rs += __shfl_xor(rs, 1);
            rs += __shfl_xor(rs, 2);
            rs += __shfl_xor(rs, 4);
            rs += __shfl_xor(rs, 8);
            lrun[r] = lrun[r] * alpha[r] + rs;
        }
        for (int i = 0; i < 16; ++i)
            for (int r = 0; r < 4; ++r) O[i][r] *= alpha[r];

        // P (C-layout) -> LDS -> A-layout bf16
        for (int f = 0; f < 2; ++f)
            for (int r = 0; r < 4; ++r)
                P_lds[lg * 4 + r][f * 16 + l15] = f2bf(S[f][r]);
        asm volatile("s_waitcnt lgkmcnt(0)" ::: "memory");
        __builtin_amdgcn_sched_barrier(0);
        s16x8 pa = *(const s16x8*)(&P_lds[l15][lg * 8]);

        // O += P * V^T   (B[k=m][col=c] = V[c][m] from LDS)
        for (int cb = 0; cb < 16; ++cb) {
            int row = cb * 16 + l15;
            int lo = row * 64 + lg * 16;
            s16x8 vb = *(const s16x8*)(Vl + (lo ^ (((row >> 1) & 3) << 4)));
            O[cb] = __builtin_amdgcn_mfma_f32_16x16x32_bf16(pa, vb, O[cb], 0, 0, 0);
        }

        __syncthreads();   // drains vmcnt(0) (prefetch done) + all waves done with cur
        cur ^= 1;
    }

    float* Ob = Opart + (size_t)(b * nsplit + split) * N_ * C_;
    float* mlb = ml + (size_t)(b * nsplit + split) * N_ * 2;
    for (int cb = 0; cb < 16; ++cb)
        for (int r = 0; r < 4; ++r)
            Ob[(size_t)(n0 + lg * 4 + r) * C_ + cb * 16 + l15] = O[cb][r];
    if (l15 == 0)
        for (int r = 0; r < 4; ++r) {
            int n = n0 + lg * 4 + r;
            mlb[(size_t)n * 2] = mrun[r];
            mlb[(size_t)n * 2 + 1] = lrun[r];
        }
}

// ---------------- merge partials -> ao bf16 [b][n][c] ----------------
__global__ __launch_bounds__(256) void attn_merge_kernel(const float* __restrict__ Opart,
                                                         const float* __restrict__ ml,
                                                         unsigned short* __restrict__ ao,
                                                         int nsplit) {
    int b = blockIdx.y;
    int n = blockIdx.x;
    int c = threadIdx.x;
    float M = -1e30f;
    for (int s = 0; s < nsplit; ++s)
        M = fmaxf(M, ml[((size_t)(b * nsplit + s) * N_ + n) * 2]);
    float L = 0.f, o = 0.f;
    for (int s = 0; s < nsplit; ++s) {
        const float* mlp = ml + ((size_t)(b * nsplit + s) * N_ + n) * 2;
        float wgt = __expf(mlp[0] - M);
        L += mlp[1] * wgt;
        o += Opart[((size_t)(b * nsplit + s) * N_ + n) * C_ + c] * wgt;
    }
    ao[((size_t)b * N_ + n) * C_ + c] = f2bf(o / L);
}

extern "C" void kernel_launch(void* const* d_in, const int* in_sizes, int n_in,
                              void* d_out, int out_size, void* d_ws, size_t ws_size,
                              hipStream_t stream) {
    const float* x = (const float*)d_in[0];
    const float* gamma = (const float*)d_in[1];
    const float* beta = (const float*)d_in[2];
    const float* wq = (const float*)d_in[3];
    const float* bq = (const float*)d_in[4];
    const float* wk = (const float*)d_in[5];
    const float* bk = (const float*)d_in[6];
    const float* wv = (const float*)d_in[7];
    const float* bv = (const float*)d_in[8];
    const float* wp = (const float*)d_in[9];
    const float* bp = (const float*)d_in[10];
    float* out = (float*)d_out;

    const size_t sz = (size_t)B_ * N_ * C_;
    unsigned short* hn = (unsigned short*)d_ws;  // [b][n][c]
    unsigned short* qt = hn + sz;                // [b][n][c], scaled
    unsigned short* kt = qt + sz;                // [b][n][c]
    unsigned short* vmat = kt + sz;              // [b][c][m]
    unsigned short* ao = vmat + sz;              // [b][n][c]
    float* Opart = (float*)(ao + sz);            // [b][s][n][c] f32, unnormalized
    // pick the largest KV-split count whose partial buffers fit in ws
    int nsplit = 4;
    while (nsplit > 1 &&
           (size_t)5 * sz * 2 + (size_t)nsplit * sz * 4 + (size_t)nsplit * B_ * N_ * 2 * 4 > ws_size)
        nsplit >>= 1;
    float* ml = Opart + (size_t)nsplit * sz;     // [b][s][n][2]

    hipLaunchKernelGGL(gn_kernel, dim3(64), dim3(256), 0, stream, x, gamma, beta, hn);
    dim3 gg(64, 2, 2);
    hipLaunchKernelGGL((gemm_kernel<0>), gg, dim3(256), 0, stream, wq, bq, hn, qt, (float*)nullptr, (const float*)nullptr, 0.0625f);
    hipLaunchKernelGGL((gemm_kernel<0>), gg, dim3(256), 0, stream, wk, bk, hn, kt, (float*)nullptr, (const float*)nullptr, 1.0f);
    hipLaunchKernelGGL((gemm_kernel<1>), gg, dim3(256), 0, stream, wv, bv, hn, vmat, (float*)nullptr, (const float*)nullptr, 1.0f);
    hipLaunchKernelGGL(attn_partial_kernel, dim3(64, nsplit, 2), dim3(256), 0, stream,
                       qt, kt, vmat, Opart, ml, N_ / nsplit);
    hipLaunchKernelGGL(attn_merge_kernel, dim3(N_, 2), dim3(256), 0, stream, Opart, ml, ao, nsplit);
    hipLaunchKernelGGL((gemm_kernel<2>), gg, dim3(256), 0, stream, wp, bp, ao, (unsigned short*)nullptr, out, x, 1.0f);
}

// Round 4
// 166.271 us; speedup vs baseline: 3.4300x; 1.1152x over previous
//
#include <hip/hip_runtime.h>
#include <hip/hip_bf16.h>

using f32x4 = __attribute__((ext_vector_type(4))) float;
using s16x8 = __attribute__((ext_vector_type(8))) short;
using s16x4 = __attribute__((ext_vector_type(4))) short;

#define B_ 2
#define C_ 256
#define N_ 4096
#define KVB 32
#define LOG2E 1.4426950408889634f

__device__ inline unsigned short f2bf(float f) {
    union { float f; unsigned u; } x{f};
    unsigned r = x.u + 0x7fffu + ((x.u >> 16) & 1u);
    return (unsigned short)(r >> 16);
}

__device__ inline float bf2f(unsigned short u) {
    union { unsigned u; float f; } x{(unsigned)u << 16};
    return x.f;
}

__device__ inline void load_lds16(const void* g, void* l) {
    __builtin_amdgcn_global_load_lds((const __attribute__((address_space(1))) void*)g,
                                     (__attribute__((address_space(3))) void*)l, 16, 0, 0);
}

// ---------------- GroupNorm: x (b,c,h,w,d) -> hn_t[b][n][c] bf16 ----------------
__global__ __launch_bounds__(256) void gn_kernel(const float* __restrict__ x,
                                                 const float* __restrict__ gamma,
                                                 const float* __restrict__ beta,
                                                 unsigned short* __restrict__ hn_t) {
    int blk = blockIdx.x;            // b*32 + group
    int b = blk >> 5, grp = blk & 31;
    const float* xb = x + ((size_t)b * C_ + grp * 8) * N_;   // 8 channels x 4096
    int t = threadIdx.x;

    float s = 0.f, sq = 0.f;
    const float4* x4 = (const float4*)xb;
    for (int i = 0; i < 32; ++i) {
        float4 v = x4[t + i * 256];
        s += v.x + v.y + v.z + v.w;
        sq += v.x * v.x + v.y * v.y + v.z * v.z + v.w * v.w;
    }
    for (int off = 32; off; off >>= 1) {
        s += __shfl_down(s, off);
        sq += __shfl_down(sq, off);
    }
    __shared__ float red[2][4];
    int wid = t >> 6;
    if ((t & 63) == 0) { red[0][wid] = s; red[1][wid] = sq; }
    __syncthreads();
    __shared__ float stats[2];
    if (t == 0) {
        float S = red[0][0] + red[0][1] + red[0][2] + red[0][3];
        float Q = red[1][0] + red[1][1] + red[1][2] + red[1][3];
        float mean = S / 32768.f;
        float var = Q / 32768.f - mean * mean;
        stats[0] = mean;
        stats[1] = rsqrtf(var + 1e-6f);
    }
    __syncthreads();
    float mean = stats[0], rstd = stats[1];

    float gm[8], bt[8];
    for (int j = 0; j < 8; ++j) {
        gm[j] = gamma[grp * 8 + j] * rstd;
        bt[j] = beta[grp * 8 + j] - mean * gm[j];
    }
    unsigned short* outp = hn_t + (size_t)b * N_ * C_ + grp * 8;
    for (int i = 0; i < 16; ++i) {
        int n = t + i * 256;
        s16x8 pk;
        for (int j = 0; j < 8; ++j) {
            float v = xb[(size_t)j * N_ + n];
            pk[j] = (short)f2bf(v * gm[j] + bt[j]);
        }
        *(s16x8*)(outp + (size_t)n * C_) = pk;
    }
}

// ---------------- W f32 -> bf16 (4 matrices) ----------------
__global__ __launch_bounds__(256) void wcvt_kernel(const float* __restrict__ wq,
                                                   const float* __restrict__ wk,
                                                   const float* __restrict__ wv,
                                                   const float* __restrict__ wp,
                                                   unsigned short* __restrict__ wbf) {
    int g = blockIdx.y;
    const float* src = g == 0 ? wq : g == 1 ? wk : g == 2 ? wv : wp;
    int idx = (blockIdx.x * 256 + threadIdx.x) * 4;
    float4 v = *(const float4*)(src + idx);
    s16x4 pk;
    pk[0] = (short)f2bf(v.x); pk[1] = (short)f2bf(v.y);
    pk[2] = (short)f2bf(v.z); pk[3] = (short)f2bf(v.w);
    *(s16x4*)(wbf + g * 65536 + idx) = pk;
}

// ---------------- GEMM core: 128o x 64n tile, BK=64, dbuf, global_load_lds ----------------
// W bf16 [256][256] (rows 512B), Bmat bf16 [4096][256] (rows 512B).
// LDS tiles row-stride 128B, XOR swizzle byte ^= ((byte>>7)&7)<<4 (applied via source).
__device__ inline void gemm_core(const unsigned short* __restrict__ Wg,
                                 const unsigned short* __restrict__ Bg,
                                 int o0, int n0, int t, f32x4 (&acc)[4][2],
                                 unsigned short (*At)[128 * 64], unsigned short (*Bt)[64 * 64]) {
    int lane = t & 63, w = t >> 6, l15 = lane & 15, lg = lane >> 4;
    int wo = (w >> 1) * 64, wn = (w & 1) * 32;
    int aoff[4], boff[2];
    for (int i = 0; i < 4; ++i) {
        int p = i * 4096 + t * 16;
        int y = p ^ (((p >> 7) & 7) << 4);
        aoff[i] = (o0 + (y >> 7)) * 512 + (y & 127);
    }
    for (int i = 0; i < 2; ++i) {
        int p = i * 4096 + t * 16;
        int y = p ^ (((p >> 7) & 7) << 4);
        boff[i] = (n0 + (y >> 7)) * 512 + (y & 127);
    }
    const char* Wc = (const char*)Wg;
    const char* Bc = (const char*)Bg;
    int cur = 0;
    for (int i = 0; i < 4; ++i)
        load_lds16(Wc + aoff[i], (char*)At[0] + i * 4096 + w * 1024);
    for (int i = 0; i < 2; ++i)
        load_lds16(Bc + boff[i], (char*)Bt[0] + i * 4096 + w * 1024);
    __syncthreads();
    for (int s = 0; s < 4; ++s) {
        if (s < 3) {
            int k2 = (s + 1) * 128;   // k0 * 2 bytes
            for (int i = 0; i < 4; ++i)
                load_lds16(Wc + aoff[i] + k2, (char*)At[cur ^ 1] + i * 4096 + w * 1024);
            for (int i = 0; i < 2; ++i)
                load_lds16(Bc + boff[i] + k2, (char*)Bt[cur ^ 1] + i * 4096 + w * 1024);
        }
        const char* Al = (const char*)At[cur];
        const char* Bl = (const char*)Bt[cur];
        for (int kk = 0; kk < 2; ++kk) {
            s16x8 af[4], bfv[2];
            for (int mi = 0; mi < 4; ++mi) {
                int row = wo + mi * 16 + l15;
                int lo = row * 128 + kk * 64 + lg * 16;
                af[mi] = *(const s16x8*)(Al + (lo ^ ((row & 7) << 4)));
            }
            for (int ni = 0; ni < 2; ++ni) {
                int row = wn + ni * 16 + l15;
                int lo = row * 128 + kk * 64 + lg * 16;
                bfv[ni] = *(const s16x8*)(Bl + (lo ^ ((row & 7) << 4)));
            }
            for (int mi = 0; mi < 4; ++mi)
                for (int ni = 0; ni < 2; ++ni)
                    acc[mi][ni] = __builtin_amdgcn_mfma_f32_16x16x32_bf16(af[mi], bfv[ni], acc[mi][ni], 0, 0, 0);
        }
        __syncthreads();
        cur ^= 1;
    }
}

// ---------------- fused QKV GEMM (z = b*3 + g) ----------------
__global__ __launch_bounds__(256) void qkv_gemm_kernel(const unsigned short* __restrict__ wbf,
                                                       const float* __restrict__ bq,
                                                       const float* __restrict__ bk,
                                                       const float* __restrict__ bv,
                                                       const unsigned short* __restrict__ hn,
                                                       unsigned short* __restrict__ qt,
                                                       unsigned short* __restrict__ kt,
                                                       unsigned short* __restrict__ v2t) {
    __shared__ unsigned short At[2][128 * 64];
    __shared__ unsigned short Bt[2][64 * 64];
    int g = blockIdx.z % 3, b = blockIdx.z / 3;
    const float* bias = g == 0 ? bq : g == 1 ? bk : bv;
    float scale = g == 0 ? 0.0625f * LOG2E : 1.0f;
    int o0 = blockIdx.y * 128, n0 = blockIdx.x * 64;
    int t = threadIdx.x;
    const size_t sz = (size_t)N_ * C_;

    f32x4 acc[4][2];
    for (int mi = 0; mi < 4; ++mi)
        for (int ni = 0; ni < 2; ++ni)
            acc[mi][ni] = (f32x4){0.f, 0.f, 0.f, 0.f};
    gemm_core(wbf + g * 65536, hn + b * sz, o0, n0, t, acc, At, Bt);

    int lane = t & 63, w = t >> 6, l15 = lane & 15, lg = lane >> 4;
    int wo = (w >> 1) * 64, wn = (w & 1) * 32;
    for (int mi = 0; mi < 4; ++mi)
        for (int ni = 0; ni < 2; ++ni)
            for (int r = 0; r < 4; ++r) {
                int o = o0 + wo + mi * 16 + lg * 4 + r;
                int n = n0 + wn + ni * 16 + l15;
                float val = (acc[mi][ni][r] + bias[o]) * scale;
                if (g <= 1) {
                    unsigned short* dst = (g == 0 ? qt : kt) + b * sz;
                    dst[(size_t)n * C_ + o] = f2bf(val);
                } else {
                    v2t[b * sz + (size_t)(n >> 5) * 8192 + o * 32 + (n & 31)] = f2bf(val);
                }
            }
}

// ---------------- output projection GEMM + residual ----------------
__global__ __launch_bounds__(256) void proj_gemm_kernel(const unsigned short* __restrict__ wbf,
                                                        const float* __restrict__ bp,
                                                        const unsigned short* __restrict__ ao,
                                                        const float* __restrict__ x,
                                                        float* __restrict__ out) {
    __shared__ unsigned short At[2][128 * 64];
    __shared__ unsigned short Bt[2][64 * 64];
    int b = blockIdx.z;
    int o0 = blockIdx.y * 128, n0 = blockIdx.x * 64;
    int t = threadIdx.x;
    const size_t sz = (size_t)N_ * C_;

    f32x4 acc[4][2];
    for (int mi = 0; mi < 4; ++mi)
        for (int ni = 0; ni < 2; ++ni)
            acc[mi][ni] = (f32x4){0.f, 0.f, 0.f, 0.f};
    gemm_core(wbf + 3 * 65536, ao + b * sz, o0, n0, t, acc, At, Bt);

    int lane = t & 63, w = t >> 6, l15 = lane & 15, lg = lane >> 4;
    int wo = (w >> 1) * 64, wn = (w & 1) * 32;
    for (int mi = 0; mi < 4; ++mi)
        for (int ni = 0; ni < 2; ++ni)
            for (int r = 0; r < 4; ++r) {
                int o = o0 + wo + mi * 16 + lg * 4 + r;
                int n = n0 + wn + ni * 16 + l15;
                size_t idx = b * sz + (size_t)o * N_ + n;
                out[idx] = x[idx] + acc[mi][ni][r] + bp[o];
            }
}

// ---------------- Flash attention, KV-split, LDS-staged K/V, defer-max ----------------
// qt/kt: [b][n][c] bf16 (Q pre-scaled by log2e/16). v2t: [b][m/32][c][32] bf16 tiles.
// S computed in log2 domain; softmax fast path has no shuffles / no rescale;
// row-sum l accumulated via MFMA against an all-ones B fragment.
__global__ __launch_bounds__(256) void attn_partial_kernel(const unsigned short* __restrict__ qt,
                                                           const unsigned short* __restrict__ kt,
                                                           const unsigned short* __restrict__ v2t,
                                                           unsigned short* __restrict__ Opart,
                                                           float* __restrict__ ml,
                                                           int kvlen) {
    int b = blockIdx.z, split = blockIdx.y, nsplit = gridDim.y;
    int t = threadIdx.x, lane = t & 63, w = t >> 6, l15 = lane & 15, lg = lane >> 4;
    int n0 = blockIdx.x * 64 + w * 16;
    const size_t off = (size_t)b * N_ * C_;
    const unsigned short* Q = qt + off;
    const char* Kg0 = (const char*)(kt + off);
    const char* Vg0 = (const char*)(v2t + off);

    __shared__ unsigned short Ktile[2][KVB * 256];
    __shared__ unsigned short Vtile[2][256 * KVB];
    __shared__ unsigned short P_all[4][16][40];
    unsigned short(*P_lds)[40] = P_all[w];

    s16x8 q[8];
    for (int f = 0; f < 8; ++f)
        q[f] = *(const s16x8*)(Q + (size_t)(n0 + l15) * C_ + f * 32 + lg * 8);

    s16x8 ones;
    for (int j = 0; j < 8; ++j) ones[j] = (short)0x3F80;   // bf16 1.0

    f32x4 O[16];
    for (int i = 0; i < 16; ++i) O[i] = (f32x4){0.f, 0.f, 0.f, 0.f};
    f32x4 lsum = (f32x4){0.f, 0.f, 0.f, 0.f};
    float mrun[4];
    for (int r = 0; r < 4; ++r) mrun[r] = -1e30f;

    int yk[4], yv[4];
    for (int i = 0; i < 4; ++i) {
        int p = i * 4096 + t * 16;
        yk[i] = p ^ (((p >> 9) & 7) << 4);
        yv[i] = p ^ (((p >> 7) & 3) << 4);
    }

    auto stage = [&](int buf, int it) {
        int m0 = split * kvlen + it * KVB;
        const char* kb = Kg0 + (size_t)m0 * 512;
        const char* vb = Vg0 + (size_t)(m0 >> 5) * 16384;
        char* Kl = (char*)&Ktile[buf][0];
        char* Vl = (char*)&Vtile[buf][0];
        for (int i = 0; i < 4; ++i)
            load_lds16(kb + yk[i], Kl + i * 4096 + w * 1024);
        for (int i = 0; i < 4; ++i)
            load_lds16(vb + yv[i], Vl + i * 4096 + w * 1024);
    };

    int niter = kvlen / KVB;
    int cur = 0;
    stage(0, 0);
    __syncthreads();

    for (int it = 0; it < niter; ++it) {
        if (it + 1 < niter) stage(cur ^ 1, it + 1);

        const char* Kl = (const char*)&Ktile[cur][0];
        const char* Vl = (const char*)&Vtile[cur][0];

        f32x4 S[2];
        __builtin_amdgcn_s_setprio(1);
        for (int f = 0; f < 2; ++f) {
            f32x4 s = (f32x4){0.f, 0.f, 0.f, 0.f};
            int row = f * 16 + l15;
            int swz = (row & 7) << 4;
            for (int kc = 0; kc < 8; ++kc) {
                int lo = row * 512 + kc * 64 + lg * 16;
                s16x8 kb2 = *(const s16x8*)(Kl + (lo ^ swz));
                s = __builtin_amdgcn_mfma_f32_16x16x32_bf16(q[kc], kb2, s, 0, 0, 0);
            }
            S[f] = s;
        }
        __builtin_amdgcn_s_setprio(0);

        // defer-max check (log2 domain, THR = 11 ~ ln-domain 8)
        float fm[4];
        bool ok = true;
        for (int r = 0; r < 4; ++r) {
            fm[r] = fmaxf(S[0][r], S[1][r]);
            ok = ok && (fm[r] <= mrun[r] + 11.0f);
        }
        if (!__all(ok)) {
            float alpha[4];
            for (int r = 0; r < 4; ++r) {
                float mx = fm[r];
                mx = fmaxf(mx, __shfl_xor(mx, 1));
                mx = fmaxf(mx, __shfl_xor(mx, 2));
                mx = fmaxf(mx, __shfl_xor(mx, 4));
                mx = fmaxf(mx, __shfl_xor(mx, 8));
                float newm = fmaxf(mrun[r], mx);
                alpha[r] = __builtin_amdgcn_exp2f(mrun[r] - newm);
                mrun[r] = newm;
                lsum[r] *= alpha[r];
            }
            for (int i = 0; i < 16; ++i)
                for (int r = 0; r < 4; ++r) O[i][r] *= alpha[r];
        }

        // P = 2^(S - m), pack to LDS (C-layout -> A-layout)
        for (int f = 0; f < 2; ++f)
            for (int r = 0; r < 4; ++r)
                P_lds[lg * 4 + r][f * 16 + l15] = f2bf(__builtin_amdgcn_exp2f(S[f][r] - mrun[r]));
        asm volatile("s_waitcnt lgkmcnt(0)" ::: "memory");
        __builtin_amdgcn_sched_barrier(0);
        s16x8 pa = *(const s16x8*)(&P_lds[l15][lg * 8]);

        __builtin_amdgcn_s_setprio(1);
        lsum = __builtin_amdgcn_mfma_f32_16x16x32_bf16(pa, ones, lsum, 0, 0, 0);
        for (int cb = 0; cb < 16; ++cb) {
            int row = cb * 16 + l15;
            int lo = row * 64 + lg * 16;
            s16x8 vb2 = *(const s16x8*)(Vl + (lo ^ (((row >> 1) & 3) << 4)));
            O[cb] = __builtin_amdgcn_mfma_f32_16x16x32_bf16(pa, vb2, O[cb], 0, 0, 0);
        }
        __builtin_amdgcn_s_setprio(0);

        __syncthreads();
        cur ^= 1;
    }

    unsigned short* Ob = Opart + (size_t)(b * nsplit + split) * N_ * C_;
    float* mlb = ml + (size_t)(b * nsplit + split) * N_ * 2;
    for (int cb = 0; cb < 16; ++cb)
        for (int r = 0; r < 4; ++r)
            Ob[(size_t)(n0 + lg * 4 + r) * C_ + cb * 16 + l15] = f2bf(O[cb][r]);
    if (l15 == 0)
        for (int r = 0; r < 4; ++r) {
            int n = n0 + lg * 4 + r;
            mlb[n * 2] = mrun[r];
            mlb[n * 2 + 1] = lsum[r];
        }
}

// ---------------- merge partials -> ao bf16 [b][n][c] ----------------
__global__ __launch_bounds__(256) void attn_merge_kernel(const unsigned short* __restrict__ Opart,
                                                         const float* __restrict__ ml,
                                                         unsigned short* __restrict__ ao,
                                                         int nsplit) {
    int b = blockIdx.y, n = blockIdx.x, c = threadIdx.x;
    float M = -1e30f;
    for (int s = 0; s < nsplit; ++s)
        M = fmaxf(M, ml[((size_t)(b * nsplit + s) * N_ + n) * 2]);
    float L = 0.f, o = 0.f;
    for (int s = 0; s < nsplit; ++s) {
        const float* mlp = ml + ((size_t)(b * nsplit + s) * N_ + n) * 2;
        float wgt = __builtin_amdgcn_exp2f(mlp[0] - M);
        L += mlp[1] * wgt;
        o += bf2f(Opart[((size_t)(b * nsplit + s) * N_ + n) * C_ + c]) * wgt;
    }
    ao[((size_t)b * N_ + n) * C_ + c] = f2bf(o / L);
}

extern "C" void kernel_launch(void* const* d_in, const int* in_sizes, int n_in,
                              void* d_out, int out_size, void* d_ws, size_t ws_size,
                              hipStream_t stream) {
    const float* x = (const float*)d_in[0];
    const float* gamma = (const float*)d_in[1];
    const float* beta = (const float*)d_in[2];
    const float* wq = (const float*)d_in[3];
    const float* bq = (const float*)d_in[4];
    const float* wk = (const float*)d_in[5];
    const float* bk = (const float*)d_in[6];
    const float* wv = (const float*)d_in[7];
    const float* bv = (const float*)d_in[8];
    const float* wp = (const float*)d_in[9];
    const float* bp = (const float*)d_in[10];
    float* out = (float*)d_out;

    const size_t sz = (size_t)B_ * N_ * C_;
    unsigned short* hn = (unsigned short*)d_ws;  // [b][n][c]
    unsigned short* qt = hn + sz;                // [b][n][c], scaled by log2e/16
    unsigned short* kt = qt + sz;                // [b][n][c]
    unsigned short* v2t = kt + sz;               // [b][m/32][c][32]
    unsigned short* ao = v2t + sz;               // [b][n][c]
    unsigned short* wbf = ao + sz;               // 4 x 256 x 256 bf16
    unsigned short* Opart = wbf + 4 * 65536;     // [b][s][n][c] bf16, unnormalized
    int nsplit = 4;
    while (nsplit > 1 &&
           (5 * sz + 262144 + (size_t)nsplit * sz) * 2 + (size_t)nsplit * B_ * N_ * 8 > ws_size)
        nsplit >>= 1;
    float* ml = (float*)(Opart + (size_t)nsplit * sz);   // [b][s][n][2] (log2-domain m, l)

    hipLaunchKernelGGL(gn_kernel, dim3(64), dim3(256), 0, stream, x, gamma, beta, hn);
    hipLaunchKernelGGL(wcvt_kernel, dim3(64, 4), dim3(256), 0, stream, wq, wk, wv, wp, wbf);
    hipLaunchKernelGGL(qkv_gemm_kernel, dim3(64, 2, 6), dim3(256), 0, stream,
                       wbf, bq, bk, bv, hn, qt, kt, v2t);
    hipLaunchKernelGGL(attn_partial_kernel, dim3(64, nsplit, 2), dim3(256), 0, stream,
                       qt, kt, v2t, Opart, ml, N_ / nsplit);
    hipLaunchKernelGGL(attn_merge_kernel, dim3(N_, 2), dim3(256), 0, stream, Opart, ml, ao, nsplit);
    hipLaunchKernelGGL(proj_gemm_kernel, dim3(64, 2, 2), dim3(256), 0, stream, wbf, bp, ao, x, out);
}

// Round 5
// 110.794 us; speedup vs baseline: 5.1475x; 1.5007x over previous
//
#include <hip/hip_runtime.h>
#include <hip/hip_bf16.h>

using f32x4 = __attribute__((ext_vector_type(4))) float;
using s16x8 = __attribute__((ext_vector_type(8))) short;
using s16x4 = __attribute__((ext_vector_type(4))) short;

#define B_ 2
#define C_ 256
#define N_ 4096
#define KVB 32
#define LOG2E 1.4426950408889634f

__device__ inline unsigned short f2bf(float f) {
    union { float f; unsigned u; } x{f};
    unsigned r = x.u + 0x7fffu + ((x.u >> 16) & 1u);
    return (unsigned short)(r >> 16);
}

__device__ inline float bf2f(unsigned short u) {
    union { unsigned u; float f; } x{(unsigned)u << 16};
    return x.f;
}

__device__ inline unsigned cvtpk(float lo, float hi) {
    unsigned r;
    asm("v_cvt_pk_bf16_f32 %0, %1, %2" : "=v"(r) : "v"(lo), "v"(hi));
    return r;
}

__device__ inline void load_lds16(const void* g, void* l) {
    __builtin_amdgcn_global_load_lds((const __attribute__((address_space(1))) void*)g,
                                     (__attribute__((address_space(3))) void*)l, 16, 0, 0);
}

// ---------------- GroupNorm: x (b,c,h,w,d) -> hn_t[b][n][c] bf16 ----------------
__global__ __launch_bounds__(256) void gn_kernel(const float* __restrict__ x,
                                                 const float* __restrict__ gamma,
                                                 const float* __restrict__ beta,
                                                 unsigned short* __restrict__ hn_t) {
    int blk = blockIdx.x;            // b*32 + group
    int b = blk >> 5, grp = blk & 31;
    const float* xb = x + ((size_t)b * C_ + grp * 8) * N_;   // 8 channels x 4096
    int t = threadIdx.x;

    float s = 0.f, sq = 0.f;
    const float4* x4 = (const float4*)xb;
    for (int i = 0; i < 32; ++i) {
        float4 v = x4[t + i * 256];
        s += v.x + v.y + v.z + v.w;
        sq += v.x * v.x + v.y * v.y + v.z * v.z + v.w * v.w;
    }
    for (int off = 32; off; off >>= 1) {
        s += __shfl_down(s, off);
        sq += __shfl_down(sq, off);
    }
    __shared__ float red[2][4];
    int wid = t >> 6;
    if ((t & 63) == 0) { red[0][wid] = s; red[1][wid] = sq; }
    __syncthreads();
    __shared__ float stats[2];
    if (t == 0) {
        float S = red[0][0] + red[0][1] + red[0][2] + red[0][3];
        float Q = red[1][0] + red[1][1] + red[1][2] + red[1][3];
        float mean = S / 32768.f;
        float var = Q / 32768.f - mean * mean;
        stats[0] = mean;
        stats[1] = rsqrtf(var + 1e-6f);
    }
    __syncthreads();
    float mean = stats[0], rstd = stats[1];

    float gm[8], bt[8];
    for (int j = 0; j < 8; ++j) {
        gm[j] = gamma[grp * 8 + j] * rstd;
        bt[j] = beta[grp * 8 + j] - mean * gm[j];
    }
    unsigned short* outp = hn_t + (size_t)b * N_ * C_ + grp * 8;
    for (int i = 0; i < 16; ++i) {
        int n = t + i * 256;
        s16x8 pk;
        for (int j = 0; j < 8; ++j) {
            float v = xb[(size_t)j * N_ + n];
            pk[j] = (short)f2bf(v * gm[j] + bt[j]);
        }
        *(s16x8*)(outp + (size_t)n * C_) = pk;
    }
}

// ---------------- W f32 -> bf16 (4 matrices) ----------------
__global__ __launch_bounds__(256) void wcvt_kernel(const float* __restrict__ wq,
                                                   const float* __restrict__ wk,
                                                   const float* __restrict__ wv,
                                                   const float* __restrict__ wp,
                                                   unsigned short* __restrict__ wbf) {
    int g = blockIdx.y;
    const float* src = g == 0 ? wq : g == 1 ? wk : g == 2 ? wv : wp;
    int idx = (blockIdx.x * 256 + threadIdx.x) * 4;
    float4 v = *(const float4*)(src + idx);
    s16x4 pk;
    pk[0] = (short)f2bf(v.x); pk[1] = (short)f2bf(v.y);
    pk[2] = (short)f2bf(v.z); pk[3] = (short)f2bf(v.w);
    *(s16x4*)(wbf + g * 65536 + idx) = pk;
}

// ---------------- GEMM core: 128o x 64n tile, BK=64, dbuf, global_load_lds ----------------
__device__ inline void gemm_core(const unsigned short* __restrict__ Wg,
                                 const unsigned short* __restrict__ Bg,
                                 int o0, int n0, int t, f32x4 (&acc)[4][2],
                                 unsigned short (*At)[128 * 64], unsigned short (*Bt)[64 * 64]) {
    int lane = t & 63, w = t >> 6, l15 = lane & 15, lg = lane >> 4;
    int wo = (w >> 1) * 64, wn = (w & 1) * 32;
    int aoff[4], boff[2];
    for (int i = 0; i < 4; ++i) {
        int p = i * 4096 + t * 16;
        int y = p ^ (((p >> 7) & 7) << 4);
        aoff[i] = (o0 + (y >> 7)) * 512 + (y & 127);
    }
    for (int i = 0; i < 2; ++i) {
        int p = i * 4096 + t * 16;
        int y = p ^ (((p >> 7) & 7) << 4);
        boff[i] = (n0 + (y >> 7)) * 512 + (y & 127);
    }
    const char* Wc = (const char*)Wg;
    const char* Bc = (const char*)Bg;
    int cur = 0;
    for (int i = 0; i < 4; ++i)
        load_lds16(Wc + aoff[i], (char*)At[0] + i * 4096 + w * 1024);
    for (int i = 0; i < 2; ++i)
        load_lds16(Bc + boff[i], (char*)Bt[0] + i * 4096 + w * 1024);
    __syncthreads();
    for (int s = 0; s < 4; ++s) {
        if (s < 3) {
            int k2 = (s + 1) * 128;   // k0 * 2 bytes
            for (int i = 0; i < 4; ++i)
                load_lds16(Wc + aoff[i] + k2, (char*)At[cur ^ 1] + i * 4096 + w * 1024);
            for (int i = 0; i < 2; ++i)
                load_lds16(Bc + boff[i] + k2, (char*)Bt[cur ^ 1] + i * 4096 + w * 1024);
        }
        const char* Al = (const char*)At[cur];
        const char* Bl = (const char*)Bt[cur];
        for (int kk = 0; kk < 2; ++kk) {
            s16x8 af[4], bfv[2];
            for (int mi = 0; mi < 4; ++mi) {
                int row = wo + mi * 16 + l15;
                int lo = row * 128 + kk * 64 + lg * 16;
                af[mi] = *(const s16x8*)(Al + (lo ^ ((row & 7) << 4)));
            }
            for (int ni = 0; ni < 2; ++ni) {
                int row = wn + ni * 16 + l15;
                int lo = row * 128 + kk * 64 + lg * 16;
                bfv[ni] = *(const s16x8*)(Bl + (lo ^ ((row & 7) << 4)));
            }
            for (int mi = 0; mi < 4; ++mi)
                for (int ni = 0; ni < 2; ++ni)
                    acc[mi][ni] = __builtin_amdgcn_mfma_f32_16x16x32_bf16(af[mi], bfv[ni], acc[mi][ni], 0, 0, 0);
        }
        __syncthreads();
        cur ^= 1;
    }
}

// ---------------- fused QKV GEMM (z = b*3 + g) ----------------
__global__ __launch_bounds__(256) void qkv_gemm_kernel(const unsigned short* __restrict__ wbf,
                                                       const float* __restrict__ bq,
                                                       const float* __restrict__ bk,
                                                       const float* __restrict__ bv,
                                                       const unsigned short* __restrict__ hn,
                                                       unsigned short* __restrict__ qt,
                                                       unsigned short* __restrict__ kt,
                                                       unsigned short* __restrict__ v2t) {
    __shared__ unsigned short At[2][128 * 64];
    __shared__ unsigned short Bt[2][64 * 64];
    int g = blockIdx.z % 3, b = blockIdx.z / 3;
    const float* bias = g == 0 ? bq : g == 1 ? bk : bv;
    float scale = g == 0 ? 0.0625f * LOG2E : 1.0f;
    int o0 = blockIdx.y * 128, n0 = blockIdx.x * 64;
    int t = threadIdx.x;
    const size_t sz = (size_t)N_ * C_;

    f32x4 acc[4][2];
    for (int mi = 0; mi < 4; ++mi)
        for (int ni = 0; ni < 2; ++ni)
            acc[mi][ni] = (f32x4){0.f, 0.f, 0.f, 0.f};
    gemm_core(wbf + g * 65536, hn + b * sz, o0, n0, t, acc, At, Bt);

    int lane = t & 63, w = t >> 6, l15 = lane & 15, lg = lane >> 4;
    int wo = (w >> 1) * 64, wn = (w & 1) * 32;
    for (int mi = 0; mi < 4; ++mi)
        for (int ni = 0; ni < 2; ++ni)
            for (int r = 0; r < 4; ++r) {
                int o = o0 + wo + mi * 16 + lg * 4 + r;
                int n = n0 + wn + ni * 16 + l15;
                float val = (acc[mi][ni][r] + bias[o]) * scale;
                if (g <= 1) {
                    unsigned short* dst = (g == 0 ? qt : kt) + b * sz;
                    dst[(size_t)n * C_ + o] = f2bf(val);
                } else {
                    v2t[b * sz + (size_t)(n >> 5) * 8192 + o * 32 + (n & 31)] = f2bf(val);
                }
            }
}

// ---------------- output projection GEMM + residual ----------------
__global__ __launch_bounds__(256) void proj_gemm_kernel(const unsigned short* __restrict__ wbf,
                                                        const float* __restrict__ bp,
                                                        const unsigned short* __restrict__ ao,
                                                        const float* __restrict__ x,
                                                        float* __restrict__ out) {
    __shared__ unsigned short At[2][128 * 64];
    __shared__ unsigned short Bt[2][64 * 64];
    int b = blockIdx.z;
    int o0 = blockIdx.y * 128, n0 = blockIdx.x * 64;
    int t = threadIdx.x;
    const size_t sz = (size_t)N_ * C_;

    f32x4 acc[4][2];
    for (int mi = 0; mi < 4; ++mi)
        for (int ni = 0; ni < 2; ++ni)
            acc[mi][ni] = (f32x4){0.f, 0.f, 0.f, 0.f};
    gemm_core(wbf + 3 * 65536, ao + b * sz, o0, n0, t, acc, At, Bt);

    int lane = t & 63, w = t >> 6, l15 = lane & 15, lg = lane >> 4;
    int wo = (w >> 1) * 64, wn = (w & 1) * 32;
    for (int mi = 0; mi < 4; ++mi)
        for (int ni = 0; ni < 2; ++ni)
            for (int r = 0; r < 4; ++r) {
                int o = o0 + wo + mi * 16 + lg * 4 + r;
                int n = n0 + wn + ni * 16 + l15;
                size_t idx = b * sz + (size_t)o * N_ + n;
                out[idx] = x[idx] + acc[mi][ni][r] + bp[o];
            }
}

// ---------------- Flash attention, KV-split, LDS K/V, in-register P ----------------
// qt/kt: [b][n][c] bf16 (Q pre-scaled by log2e/16). v2t: [b][m/32][c][32] bf16 tiles.
// K staged with pi-permuted rows so that after S^T = mfma(K, Q), lane (lg,l15)
// holds scores for query=l15, keys {8lg..8lg+7} -> PV A-frag built with 4 cvt_pk.
__global__ __launch_bounds__(256) void attn_partial_kernel(const unsigned short* __restrict__ qt,
                                                           const unsigned short* __restrict__ kt,
                                                           const unsigned short* __restrict__ v2t,
                                                           unsigned short* __restrict__ Opart,
                                                           float* __restrict__ ml,
                                                           int kvlen) {
    int b = blockIdx.z, split = blockIdx.y, nsplit = gridDim.y;
    int t = threadIdx.x, lane = t & 63, w = t >> 6, l15 = lane & 15, lg = lane >> 4;
    int n0 = blockIdx.x * 64 + w * 16;
    const size_t off = (size_t)b * N_ * C_;
    const unsigned short* Q = qt + off;
    const char* Kg0 = (const char*)(kt + off);
    const char* Vg0 = (const char*)(v2t + off);

    __shared__ unsigned short Ktile[2][KVB * 256];
    __shared__ unsigned short Vtile[2][256 * KVB];

    s16x8 q[8];
    for (int f = 0; f < 8; ++f)
        q[f] = *(const s16x8*)(Q + (size_t)(n0 + l15) * C_ + f * 32 + lg * 8);

    f32x4 O[16];
    for (int i = 0; i < 16; ++i) O[i] = (f32x4){0.f, 0.f, 0.f, 0.f};
    float mrun = -1e30f, lsum = 0.f;

    // staging source offsets (hoisted): K with row-permutation pi + read-swizzle inverse,
    // V with read-swizzle inverse.  pi(r) = (r&3) + ((r>>2)&3)*8 + (r>>4)*4.
    int yk[4], yv[4];
    for (int i = 0; i < 4; ++i) {
        int p = i * 4096 + t * 16;
        int y = p ^ (((p >> 9) & 7) << 4);
        int row = y >> 9;
        int pr = (row & 3) + ((row >> 2) & 3) * 8 + ((row >> 4) & 1) * 4;
        yk[i] = pr * 512 + (y & 511);
        yv[i] = p ^ (((p >> 7) & 3) << 4);
    }

    auto stage = [&](int buf, int it) {
        int m0 = split * kvlen + it * KVB;
        const char* kb = Kg0 + (size_t)m0 * 512;
        const char* vb = Vg0 + (size_t)(m0 >> 5) * 16384;
        char* Kl = (char*)&Ktile[buf][0];
        char* Vl = (char*)&Vtile[buf][0];
        for (int i = 0; i < 4; ++i)
            load_lds16(kb + yk[i], Kl + i * 4096 + w * 1024);
        for (int i = 0; i < 4; ++i)
            load_lds16(vb + yv[i], Vl + i * 4096 + w * 1024);
    };

    int niter = kvlen / KVB;
    int cur = 0;
    stage(0, 0);
    __syncthreads();

    for (int it = 0; it < niter; ++it) {
        if (it + 1 < niter) stage(cur ^ 1, it + 1);

        const char* Kl = (const char*)&Ktile[cur][0];
        const char* Vl = (const char*)&Vtile[cur][0];

        // S^T = K(perm) x Q : lane holds S[q=l15][keys 8lg+4f+r]
        f32x4 S[2];
        for (int f = 0; f < 2; ++f) {
            f32x4 s = (f32x4){0.f, 0.f, 0.f, 0.f};
            int row = f * 16 + l15;
            int swz = (l15 & 7) << 4;
            for (int kc = 0; kc < 8; ++kc) {
                int lo = row * 512 + kc * 64 + lg * 16;
                s16x8 kb2 = *(const s16x8*)(Kl + (lo ^ swz));
                s = __builtin_amdgcn_mfma_f32_16x16x32_bf16(kb2, q[kc], s, 0, 0, 0);
            }
            S[f] = s;
        }

        // row max for query l15 (in-lane 8 + cross-lane-group)
        float mx = fmaxf(fmaxf(fmaxf(S[0][0], S[0][1]), fmaxf(S[0][2], S[0][3])),
                         fmaxf(fmaxf(S[1][0], S[1][1]), fmaxf(S[1][2], S[1][3])));
        mx = fmaxf(mx, __shfl_xor(mx, 16));
        mx = fmaxf(mx, __shfl_xor(mx, 32));

        // defer-max: rescale only when max grew by > 11 (log2 domain)
        if (!__all(mx <= mrun + 11.0f)) {
            float newm = fmaxf(mrun, mx);
            float alpha = __builtin_amdgcn_exp2f(mrun - newm);
            mrun = newm;
            lsum *= alpha;
            float a0 = __shfl(alpha, lg * 4 + 0);
            float a1 = __shfl(alpha, lg * 4 + 1);
            float a2 = __shfl(alpha, lg * 4 + 2);
            float a3 = __shfl(alpha, lg * 4 + 3);
            for (int i = 0; i < 16; ++i) {
                O[i][0] *= a0; O[i][1] *= a1; O[i][2] *= a2; O[i][3] *= a3;
            }
        }

        // P = 2^(S-m); in-register A-frag via cvt_pk; row-sum in VALU
        float p00 = __builtin_amdgcn_exp2f(S[0][0] - mrun);
        float p01 = __builtin_amdgcn_exp2f(S[0][1] - mrun);
        float p02 = __builtin_amdgcn_exp2f(S[0][2] - mrun);
        float p03 = __builtin_amdgcn_exp2f(S[0][3] - mrun);
        float p10 = __builtin_amdgcn_exp2f(S[1][0] - mrun);
        float p11 = __builtin_amdgcn_exp2f(S[1][1] - mrun);
        float p12 = __builtin_amdgcn_exp2f(S[1][2] - mrun);
        float p13 = __builtin_amdgcn_exp2f(S[1][3] - mrun);
        float ps = ((p00 + p01) + (p02 + p03)) + ((p10 + p11) + (p12 + p13));
        ps += __shfl_xor(ps, 16);
        ps += __shfl_xor(ps, 32);
        lsum += ps;

        union { unsigned u[4]; s16x8 v; } pk;
        pk.u[0] = cvtpk(p00, p01);
        pk.u[1] = cvtpk(p02, p03);
        pk.u[2] = cvtpk(p10, p11);
        pk.u[3] = cvtpk(p12, p13);
        s16x8 pa = pk.v;

        // O += P * V   (B-frag: V[key][c] from LDS, natural key order)
        for (int cb = 0; cb < 16; ++cb) {
            int row = cb * 16 + l15;
            int lo = row * 64 + lg * 16;
            s16x8 vb2 = *(const s16x8*)(Vl + (lo ^ (((row >> 1) & 3) << 4)));
            O[cb] = __builtin_amdgcn_mfma_f32_16x16x32_bf16(pa, vb2, O[cb], 0, 0, 0);
        }

        __syncthreads();
        cur ^= 1;
    }

    unsigned short* Ob = Opart + (size_t)(b * nsplit + split) * N_ * C_;
    float* mlb = ml + (size_t)(b * nsplit + split) * N_ * 2;
    for (int cb = 0; cb < 16; ++cb)
        for (int r = 0; r < 4; ++r)
            Ob[(size_t)(n0 + lg * 4 + r) * C_ + cb * 16 + l15] = f2bf(O[cb][r]);
    if (lane < 16) {
        int n = n0 + lane;
        mlb[n * 2] = mrun;
        mlb[n * 2 + 1] = lsum;
    }
}

// ---------------- merge partials -> ao bf16 [b][n][c] ----------------
__global__ __launch_bounds__(256) void attn_merge_kernel(const unsigned short* __restrict__ Opart,
                                                         const float* __restrict__ ml,
                                                         unsigned short* __restrict__ ao,
                                                         int nsplit) {
    int b = blockIdx.y, n = blockIdx.x, c = threadIdx.x;
    float M = -1e30f;
    for (int s = 0; s < nsplit; ++s)
        M = fmaxf(M, ml[((size_t)(b * nsplit + s) * N_ + n) * 2]);
    float L = 0.f, o = 0.f;
    for (int s = 0; s < nsplit; ++s) {
        const float* mlp = ml + ((size_t)(b * nsplit + s) * N_ + n) * 2;
        float wgt = __builtin_amdgcn_exp2f(mlp[0] - M);
        L += mlp[1] * wgt;
        o += bf2f(Opart[((size_t)(b * nsplit + s) * N_ + n) * C_ + c]) * wgt;
    }
    ao[((size_t)b * N_ + n) * C_ + c] = f2bf(o / L);
}

extern "C" void kernel_launch(void* const* d_in, const int* in_sizes, int n_in,
                              void* d_out, int out_size, void* d_ws, size_t ws_size,
                              hipStream_t stream) {
    const float* x = (const float*)d_in[0];
    const float* gamma = (const float*)d_in[1];
    const float* beta = (const float*)d_in[2];
    const float* wq = (const float*)d_in[3];
    const float* bq = (const float*)d_in[4];
    const float* wk = (const float*)d_in[5];
    const float* bk = (const float*)d_in[6];
    const float* wv = (const float*)d_in[7];
    const float* bv = (const float*)d_in[8];
    const float* wp = (const float*)d_in[9];
    const float* bp = (const float*)d_in[10];
    float* out = (float*)d_out;

    const size_t sz = (size_t)B_ * N_ * C_;
    unsigned short* hn = (unsigned short*)d_ws;  // [b][n][c]
    unsigned short* qt = hn + sz;                // [b][n][c], scaled by log2e/16
    unsigned short* kt = qt + sz;                // [b][n][c]
    unsigned short* v2t = kt + sz;               // [b][m/32][c][32]
    unsigned short* ao = v2t + sz;               // [b][n][c]
    unsigned short* wbf = ao + sz;               // 4 x 256 x 256 bf16
    unsigned short* Opart = wbf + 4 * 65536;     // [b][s][n][c] bf16, unnormalized
    int nsplit = 4;
    while (nsplit > 1 &&
           (5 * sz + 262144 + (size_t)nsplit * sz) * 2 + (size_t)nsplit * B_ * N_ * 8 > ws_size)
        nsplit >>= 1;
    float* ml = (float*)(Opart + (size_t)nsplit * sz);   // [b][s][n][2] (log2-domain m, l)

    hipLaunchKernelGGL(gn_kernel, dim3(64), dim3(256), 0, stream, x, gamma, beta, hn);
    hipLaunchKernelGGL(wcvt_kernel, dim3(64, 4), dim3(256), 0, stream, wq, wk, wv, wp, wbf);
    hipLaunchKernelGGL(qkv_gemm_kernel, dim3(64, 2, 6), dim3(256), 0, stream,
                       wbf, bq, bk, bv, hn, qt, kt, v2t);
    hipLaunchKernelGGL(attn_partial_kernel, dim3(64, nsplit, 2), dim3(256), 0, stream,
                       qt, kt, v2t, Opart, ml, N_ / nsplit);
    hipLaunchKernelGGL(attn_merge_kernel, dim3(N_, 2), dim3(256), 0, stream, Opart, ml, ao, nsplit);
    hipLaunchKernelGGL(proj_gemm_kernel, dim3(64, 2, 2), dim3(256), 0, stream, wbf, bp, ao, x, out);
}